// Round 7
// baseline (368.981 us; speedup 1.0000x reference)
//
#include <hip/hip_runtime.h>
#include <hip/hip_cooperative_groups.h>
#include <stdint.h>

namespace cg = cooperative_groups;

#define EPSF 1e-5f

typedef __attribute__((ext_vector_type(8)))  short bh8;    // 8 bf16 = 4 VGPR
typedef __attribute__((ext_vector_type(16))) float fx16;   // 32x32 MFMA acc
typedef __attribute__((ext_vector_type(4)))  int   i32x4;

__device__ __forceinline__ int cvtpk(float a, float b) {
    int r;
    asm("v_cvt_pk_bf16_f32 %0, %1, %2" : "=v"(r) : "v"(a), "v"(b));
    return r;
}

// Phase-3 LDS layout (45,776 B). All float4-cast bases are 16B-aligned.
struct P3S {
    float sWo[40][48];
    float sW1[40][32];
    float sW2[20][48];
    float sBo[40], sG2[40], sBt2[40], sB1[20], sB2[40];
    float sCtx[64][41];
    float sH[64][41];
    float sIt[64][21];
    float sSum[64][4], sSum2[64][4];
};

struct Params {
    const float *x, *g1, *be1, *Wq, *bq, *Wk, *bk, *Wv, *bv;
    const float *Wo, *bo, *g2, *bt2, *W1, *b1, *W2, *b2;
    unsigned short *q, *k, *vt;
    float *ctx, *out;
};

// ---------------- fused BERT layer: 3 phases, 2 grid syncs ----------------
// grid 512 x 256 (= exactly 2 blocks/CU on 256 CUs; launch_bounds(256,2)
// guarantees the occupancy so hipLaunchCooperativeKernel admits the grid).
// Phase bodies are identical to the previously-verified k1/k2/k3.
__global__ __launch_bounds__(256, 2) void kmega(Params P)
{
    __shared__ __align__(16) char smem[sizeof(P3S)];

    const int tid  = threadIdx.x;
    const int blk  = blockIdx.x;
    const int lane = tid & 63;
    const int wavei = tid >> 6;

    // ============ Phase 1: LN1 + QKV projection (bf16 out) ============
    // block = 64 rows; lane = row, wave = head. Q pre-scaled log2e/sqrt(10);
    // K [bh][512][16]; V^T [bh][16][512] with ones-row at d=10.
    {
        float (*sX)[41] = (float (*)[41])smem;
        const float4* xblk = (const float4*)(P.x + (size_t)blk * 64 * 40);
        for (int idx = tid; idx < 640; idx += 256) {
            float4 u = xblk[idx];
            int fl = idx * 4;
            int r = fl / 40, c = fl - r * 40;
            sX[r][c] = u.x; sX[r][c + 1] = u.y; sX[r][c + 2] = u.z; sX[r][c + 3] = u.w;
        }
        __syncthreads();

        const int hp = __builtin_amdgcn_readfirstlane(wavei);   // uniform head

        float s1 = 0.f, s2 = 0.f;
#pragma unroll 8
        for (int i = 0; i < 40; i++) { float v = sX[lane][i]; s1 += v; s2 += v * v; }
        const float mu = s1 * 0.025f;
        const float rs = rsqrtf(s2 * 0.025f - mu * mu + EPSF);

        float hrow[40];
#pragma unroll 4
        for (int i = 0; i < 40; i++)
            hrow[i] = (sX[lane][i] - mu) * rs * P.g1[i] + P.be1[i];

        const float* Wp[3] = {P.Wq, P.Wk, P.Wv};
        const float* Bp[3] = {P.bq, P.bk, P.bv};

        float acc[3][10];
#pragma unroll
        for (int w = 0; w < 3; w++)
#pragma unroll
            for (int c = 0; c < 10; c++) acc[w][c] = Bp[w][hp * 10 + c];

#pragma unroll 2
        for (int i = 0; i < 40; i++) {
            const float hi = hrow[i];
#pragma unroll
            for (int w = 0; w < 3; w++) {
                const float* wp = Wp[w] + i * 40 + hp * 10;   // uniform -> s_load
#pragma unroll
                for (int c = 0; c < 10; c++) acc[w][c] += hi * wp[c];
            }
        }

        const float cs = 1.4426950408889634f / 3.1622776601683795f;
#pragma unroll
        for (int c = 0; c < 10; c++) acc[0][c] *= cs;

        const int row0 = blk * 64;
        const int b4 = (row0 >> 9) * 4, s0 = row0 & 511;
        const size_t srow = (size_t)(b4 + hp) * 512 + s0 + lane;

        {   // Q
            int p0 = cvtpk(acc[0][0], acc[0][1]);
            int p1 = cvtpk(acc[0][2], acc[0][3]);
            int p2 = cvtpk(acc[0][4], acc[0][5]);
            int p3 = cvtpk(acc[0][6], acc[0][7]);
            int p4 = cvtpk(acc[0][8], acc[0][9]);
            i32x4* dst = (i32x4*)P.q + srow * 2;
            dst[0] = (i32x4){p0, p1, p2, p3};
            dst[1] = (i32x4){p4, 0, 0, 0};
        }
        {   // K
            int p0 = cvtpk(acc[1][0], acc[1][1]);
            int p1 = cvtpk(acc[1][2], acc[1][3]);
            int p2 = cvtpk(acc[1][4], acc[1][5]);
            int p3 = cvtpk(acc[1][6], acc[1][7]);
            int p4 = cvtpk(acc[1][8], acc[1][9]);
            i32x4* dst = (i32x4*)P.k + srow * 2;
            dst[0] = (i32x4){p0, p1, p2, p3};
            dst[1] = (i32x4){p4, 0, 0, 0};
        }
        {   // V^T scatter by d-row
            int p0 = cvtpk(acc[2][0], acc[2][1]);
            int p1 = cvtpk(acc[2][2], acc[2][3]);
            int p2 = cvtpk(acc[2][4], acc[2][5]);
            int p3 = cvtpk(acc[2][6], acc[2][7]);
            int p4 = cvtpk(acc[2][8], acc[2][9]);
            unsigned short* vb = P.vt + ((size_t)(b4 + hp) * 16) * 512 + (s0 + lane);
            vb[0 * 512] = (unsigned short)(p0 & 0xffff);
            vb[1 * 512] = (unsigned short)((unsigned)p0 >> 16);
            vb[2 * 512] = (unsigned short)(p1 & 0xffff);
            vb[3 * 512] = (unsigned short)((unsigned)p1 >> 16);
            vb[4 * 512] = (unsigned short)(p2 & 0xffff);
            vb[5 * 512] = (unsigned short)((unsigned)p2 >> 16);
            vb[6 * 512] = (unsigned short)(p3 & 0xffff);
            vb[7 * 512] = (unsigned short)((unsigned)p3 >> 16);
            vb[8 * 512] = (unsigned short)(p4 & 0xffff);
            vb[9 * 512] = (unsigned short)((unsigned)p4 >> 16);
            vb[10 * 512] = 0x3F80;   // bf16(1.0) ones-row -> denominator
            vb[11 * 512] = 0; vb[12 * 512] = 0; vb[13 * 512] = 0;
            vb[14 * 512] = 0; vb[15 * 512] = 0;
        }
    }

    __threadfence();
    cg::this_grid().sync();

    // ============ Phase 2: MFMA attention ============
    // block = (bh, q-half); 4 waves x 2 q-tiles of 32. QK^T as S^T, exp2,
    // cvt_pk + permlane32_swap into A-operand order, PV with denominator
    // accumulated via the V^T ones-row. One block barrier.
    {
        const int bh = blk >> 1;
        const int qh = blk & 1;

        bh8 qf0, qf1;
        {
            const char* qp = (const char*)P.q + (size_t)bh * 512 * 32;
            const int qbase = qh * 256 + wavei * 64;
            qf0 = *(const bh8*)(qp + (size_t)(qbase + (lane & 31)) * 32 + (lane >> 5) * 16);
            qf1 = *(const bh8*)(qp + (size_t)(qbase + 32 + (lane & 31)) * 32 + (lane >> 5) * 16);
        }
        {
            const i32x4* gk = (const i32x4*)((const char*)P.k + (size_t)bh * 512 * 32);
            for (int c = tid; c < 1024; c += 256) {
                i32x4 u = gk[c];
                *(i32x4*)(smem + (c >> 1) * 48 + (c & 1) * 16) = u;
            }
            const i32x4* gv = (const i32x4*)((const char*)P.vt + (size_t)bh * 16 * 1024);
            for (int c = tid; c < 1024; c += 256) {
                i32x4 u = gv[c];
                *(i32x4*)(smem + 24576 + (c >> 6) * 1040 + (c & 63) * 16) = u;
            }
        }
        __syncthreads();

        const char* sK = smem;
        const char* sV = smem + 24576;
        const int krow = lane & 31, khalf = lane >> 5;
        const int vrow = lane & 15;
        const bool vzero = (lane & 16) != 0;

        fx16 acc0 = (fx16)(0.0f), acc1 = (fx16)(0.0f);

        for (int kt = 0; kt < 16; ++kt) {      // 32 keys / iter
            bh8 kf  = *(const bh8*)(sK + (kt * 32 + krow) * 48 + khalf * 16);
            bh8 vf0 = *(const bh8*)(sV + vrow * 1040 + kt * 64 + khalf * 16);
            bh8 vf1 = *(const bh8*)(sV + vrow * 1040 + kt * 64 + 32 + khalf * 16);
            if (vzero) { vf0 = (bh8)(short)0; vf1 = (bh8)(short)0; }
#pragma unroll
            for (int qt = 0; qt < 2; ++qt) {
                fx16 s = __builtin_amdgcn_mfma_f32_32x32x16_bf16(
                    kf, qt ? qf1 : qf0, (fx16)(0.0f), 0, 0, 0);
                float e[16];
#pragma unroll
                for (int r = 0; r < 16; ++r) e[r] = __builtin_amdgcn_exp2f(s[r]);
                int c0 = cvtpk(e[0], e[1]),   c1 = cvtpk(e[2], e[3]);
                int c2 = cvtpk(e[4], e[5]),   c3 = cvtpk(e[6], e[7]);
                int c4 = cvtpk(e[8], e[9]),   c5 = cvtpk(e[10], e[11]);
                int c6 = cvtpk(e[12], e[13]), c7 = cvtpk(e[14], e[15]);
                asm("v_permlane32_swap_b32 %0, %1" : "+v"(c0), "+v"(c2));
                asm("v_permlane32_swap_b32 %0, %1" : "+v"(c1), "+v"(c3));
                asm("v_permlane32_swap_b32 %0, %1" : "+v"(c4), "+v"(c6));
                asm("v_permlane32_swap_b32 %0, %1" : "+v"(c5), "+v"(c7));
                union { i32x4 i; bh8 h; } lo, hi;
                lo.i = (i32x4){c0, c1, c2, c3};
                hi.i = (i32x4){c4, c5, c6, c7};
                if (qt == 0) {
                    acc0 = __builtin_amdgcn_mfma_f32_32x32x16_bf16(lo.h, vf0, acc0, 0, 0, 0);
                    acc0 = __builtin_amdgcn_mfma_f32_32x32x16_bf16(hi.h, vf1, acc0, 0, 0, 0);
                } else {
                    acc1 = __builtin_amdgcn_mfma_f32_32x32x16_bf16(lo.h, vf0, acc1, 0, 0, 0);
                    acc1 = __builtin_amdgcn_mfma_f32_32x32x16_bf16(hi.h, vf1, acc1, 0, 0, 0);
                }
            }
        }

        const int d = lane & 31;
        const int qb = qh * 256 + wavei * 64;
#pragma unroll
        for (int qt = 0; qt < 2; ++qt) {
            fx16 A = qt ? acc1 : acc0;
#pragma unroll
            for (int r = 0; r < 16; ++r) {
                float v = A[r];
                float ls = __shfl(v, (lane & 32) | 10, 64);
                float o = v / ls;
                if (d < 10) {
                    int q = qb + qt * 32 + (r & 3) + 8 * (r >> 2) + 4 * (lane >> 5);
                    P.ctx[((size_t)bh * 512 + q) * 10 + d] = o;
                }
            }
        }
    }

    __threadfence();
    cg::this_grid().sync();

    // ============ Phase 3: Wo + residual + LN2 + FFN + residual ============
    {
        P3S& S = *(P3S*)smem;

        for (int idx = tid; idx < 1600; idx += 256) {
            int i = idx / 40, j = idx % 40;
            S.sWo[i][(j / 10) * 12 + (j % 10)] = P.Wo[idx];
        }
        for (int idx = tid; idx < 800; idx += 256) {
            {
                int i = idx / 20, j = idx % 20;
                S.sW1[i][(j / 5) * 8 + (j % 5)] = P.W1[idx];
            }
            {
                int i = idx / 40, j = idx % 40;
                S.sW2[i][(j / 10) * 12 + (j % 10)] = P.W2[idx];
            }
        }
        if (tid < 40) { S.sBo[tid] = P.bo[tid]; S.sG2[tid] = P.g2[tid]; S.sBt2[tid] = P.bt2[tid]; S.sB2[tid] = P.b2[tid]; }
        if (tid < 20) S.sB1[tid] = P.b1[tid];

        const int row0 = blk * 64;
        const int b = row0 >> 9, s0 = row0 & 511;

        for (int idx = tid; idx < 640; idx += 256) {
            const int hh = idx / 160, f = idx - hh * 160;
            float4 u = *(const float4*)(P.ctx + ((size_t)((b * 4 + hh) * 512 + s0)) * 10 + f * 4);
            const int fo = f * 4;
            float e[4] = {u.x, u.y, u.z, u.w};
#pragma unroll
            for (int t = 0; t < 4; t++) {
                const int fe = fo + t;
                const int r = fe / 10, c = fe - r * 10;
                S.sCtx[r][hh * 10 + c] = e[t];
            }
        }
        const float4* xblk = (const float4*)(P.x + (size_t)blk * 64 * 40);
        for (int idx = tid; idx < 640; idx += 256) {
            float4 w = xblk[idx];
            int fl = idx * 4;
            int r = fl / 40, c = fl - r * 40;
            S.sH[r][c] = w.x; S.sH[r][c + 1] = w.y; S.sH[r][c + 2] = w.z; S.sH[r][c + 3] = w.w;
        }
        __syncthreads();

        const int j0 = wavei * 10;

        float acc[10];
#pragma unroll
        for (int j = 0; j < 10; j++) acc[j] = S.sBo[j0 + j] + S.sH[lane][j0 + j];
#pragma unroll 8
        for (int i = 0; i < 40; i++) {
            const float ci = S.sCtx[lane][i];
            const float4* wrow = (const float4*)&S.sWo[i][wavei * 12];
            float4 w0 = wrow[0], w1 = wrow[1], w2 = wrow[2];
            acc[0] += ci * w0.x; acc[1] += ci * w0.y; acc[2] += ci * w0.z; acc[3] += ci * w0.w;
            acc[4] += ci * w1.x; acc[5] += ci * w1.y; acc[6] += ci * w1.z; acc[7] += ci * w1.w;
            acc[8] += ci * w2.x; acc[9] += ci * w2.y;
        }
        {
            float s1 = 0.f, s2 = 0.f;
#pragma unroll
            for (int j = 0; j < 10; j++) { s1 += acc[j]; s2 += acc[j] * acc[j]; }
            S.sSum[lane][wavei] = s1; S.sSum2[lane][wavei] = s2;
        }
        __syncthreads();
        const float mu = (S.sSum[lane][0] + S.sSum[lane][1] + S.sSum[lane][2] + S.sSum[lane][3]) * 0.025f;
        const float ex2 = (S.sSum2[lane][0] + S.sSum2[lane][1] + S.sSum2[lane][2] + S.sSum2[lane][3]) * 0.025f;
        const float rs = rsqrtf(ex2 - mu * mu + EPSF);
#pragma unroll
        for (int j = 0; j < 10; j++)
            S.sH[lane][j0 + j] = (acc[j] - mu) * rs * S.sG2[j0 + j] + S.sBt2[j0 + j];
        __syncthreads();

        const int f0 = wavei * 5;
        float it[5];
#pragma unroll
        for (int j = 0; j < 5; j++) it[j] = S.sB1[f0 + j];
#pragma unroll 8
        for (int i = 0; i < 40; i++) {
            const float hi = S.sH[lane][i];
            const float4* wrow = (const float4*)&S.sW1[i][wavei * 8];
            float4 w0 = wrow[0], w1 = wrow[1];
            it[0] += hi * w0.x; it[1] += hi * w0.y; it[2] += hi * w0.z; it[3] += hi * w0.w;
            it[4] += hi * w1.x;
        }
#pragma unroll
        for (int j = 0; j < 5; j++) {
            float t = it[j];
            S.sIt[lane][f0 + j] = 0.5f * t * (1.0f + erff(t * 0.70710678118654752f));
        }
        __syncthreads();

        float o[10];
#pragma unroll
        for (int j = 0; j < 10; j++) o[j] = acc[j] + S.sB2[j0 + j];
#pragma unroll 4
        for (int i = 0; i < 20; i++) {
            const float ii = S.sIt[lane][i];
            const float4* wrow = (const float4*)&S.sW2[i][wavei * 12];
            float4 w0 = wrow[0], w1 = wrow[1], w2 = wrow[2];
            o[0] += ii * w0.x; o[1] += ii * w0.y; o[2] += ii * w0.z; o[3] += ii * w0.w;
            o[4] += ii * w1.x; o[5] += ii * w1.y; o[6] += ii * w1.z; o[7] += ii * w1.w;
            o[8] += ii * w2.x; o[9] += ii * w2.y;
        }
#pragma unroll
        for (int j = 0; j < 10; j++) S.sCtx[lane][j0 + j] = o[j];
        __syncthreads();

        float4* oblk = (float4*)(P.out + (size_t)blk * 64 * 40);
        for (int idx = tid; idx < 640; idx += 256) {
            int fl = idx * 4;
            int r = fl / 40, c = fl - r * 40;
            float4 u;
            u.x = S.sCtx[r][c]; u.y = S.sCtx[r][c + 1]; u.z = S.sCtx[r][c + 2]; u.w = S.sCtx[r][c + 3];
            oblk[idx] = u;
        }
    }
}

extern "C" void kernel_launch(void* const* d_in, const int* in_sizes, int n_in,
                              void* d_out, int out_size, void* d_ws, size_t ws_size,
                              hipStream_t stream)
{
    unsigned short* wsu = (unsigned short*)d_ws;
    const size_t T = (size_t)256 * 512 * 16;   // 4 MB per bf16 tensor

    Params p;
    p.x   = (const float*)d_in[0];
    p.g1  = (const float*)d_in[1];
    p.be1 = (const float*)d_in[2];
    p.Wq  = (const float*)d_in[3];
    p.bq  = (const float*)d_in[4];
    p.Wk  = (const float*)d_in[5];
    p.bk  = (const float*)d_in[6];
    p.Wv  = (const float*)d_in[7];
    p.bv  = (const float*)d_in[8];
    p.Wo  = (const float*)d_in[9];
    p.bo  = (const float*)d_in[10];
    p.g2  = (const float*)d_in[11];
    p.bt2 = (const float*)d_in[12];
    p.W1  = (const float*)d_in[13];
    p.b1  = (const float*)d_in[14];
    p.W2  = (const float*)d_in[15];
    p.b2  = (const float*)d_in[16];
    p.q   = wsu;
    p.k   = wsu + T;
    p.vt  = wsu + 2 * T;
    p.ctx = (float*)(wsu + 3 * T);
    p.out = (float*)d_out;

    void* args[] = { &p };
    hipLaunchCooperativeKernel((void*)kmega, dim3(512), dim3(256), args, 0, stream);
}

// Round 8
// 138.678 us; speedup vs baseline: 2.6607x; 2.6607x over previous
//
#include <hip/hip_runtime.h>
#include <stdint.h>

#define EPSF 1e-5f

typedef __attribute__((ext_vector_type(8)))  short bh8;    // 8 bf16 = 4 VGPR
typedef __attribute__((ext_vector_type(16))) float fx16;   // 32x32 MFMA acc
typedef __attribute__((ext_vector_type(4)))  int   i32x4;

__device__ __forceinline__ int cvtpk(float a, float b) {
    int r;
    asm("v_cvt_pk_bf16_f32 %0, %1, %2" : "=v"(r) : "v"(a), "v"(b));
    return r;
}
__device__ __forceinline__ float fastrcp(float x) {
    float r;
    asm("v_rcp_f32 %0, %1" : "=v"(r) : "v"(x));
    return r;
}

// ---------------- K1: LN1 + QKV projection (bf16 out) ----------------
// grid 512 x 256. Block = 64 rows; lane = row, wave = head (0..3).
// Emits: Q bf16 [bh][512][16] pre-scaled by log2e/sqrt(10) (d 10..15 = 0),
//        K bf16 [bh][512][16],
//        V^T bf16 [bh][16][512] with ones-row at d=10 (PV col 10 =
//        softmax denominator), rows 11..15 = 0.
__global__ __launch_bounds__(256) void k_ln_qkv(
    const float* __restrict__ x, const float* __restrict__ g, const float* __restrict__ be,
    const float* __restrict__ Wq, const float* __restrict__ bq,
    const float* __restrict__ Wk, const float* __restrict__ bk,
    const float* __restrict__ Wv, const float* __restrict__ bv,
    unsigned short* __restrict__ qo, unsigned short* __restrict__ ko,
    unsigned short* __restrict__ vt)
{
    __shared__ float sX[64][41];

    const int tid = threadIdx.x;
    const float4* xblk = (const float4*)(x + (size_t)blockIdx.x * 64 * 40);
    for (int idx = tid; idx < 640; idx += 256) {
        float4 u = xblk[idx];
        int fl = idx * 4;
        int r = fl / 40, c = fl - r * 40;
        sX[r][c] = u.x; sX[r][c + 1] = u.y; sX[r][c + 2] = u.z; sX[r][c + 3] = u.w;
    }
    __syncthreads();

    const int lane = tid & 63;
    const int part = tid >> 6;
    const int hp = __builtin_amdgcn_readfirstlane(part);   // uniform head idx

    float s1 = 0.f, s2 = 0.f;
#pragma unroll 8
    for (int i = 0; i < 40; i++) { float v = sX[lane][i]; s1 += v; s2 += v * v; }
    const float mu = s1 * 0.025f;
    const float rs = rsqrtf(s2 * 0.025f - mu * mu + EPSF);

    float hrow[40];
#pragma unroll 4
    for (int i = 0; i < 40; i++)
        hrow[i] = (sX[lane][i] - mu) * rs * g[i] + be[i];

    const float* Wp[3] = {Wq, Wk, Wv};
    const float* Bp[3] = {bq, bk, bv};

    float acc[3][10];
#pragma unroll
    for (int w = 0; w < 3; w++)
#pragma unroll
        for (int c = 0; c < 10; c++) acc[w][c] = Bp[w][hp * 10 + c];

#pragma unroll 2
    for (int i = 0; i < 40; i++) {
        const float hi = hrow[i];
#pragma unroll
        for (int w = 0; w < 3; w++) {
            const float* wp = Wp[w] + i * 40 + hp * 10;   // uniform -> s_load
#pragma unroll
            for (int c = 0; c < 10; c++) acc[w][c] += hi * wp[c];
        }
    }

    const float cs = 1.4426950408889634f / 3.1622776601683795f;  // log2e/sqrt(10)
#pragma unroll
    for (int c = 0; c < 10; c++) acc[0][c] *= cs;

    const int row0 = blockIdx.x * 64;
    const int b4 = (row0 >> 9) * 4, s0 = row0 & 511;
    const size_t srow = (size_t)(b4 + hp) * 512 + s0 + lane;

    {   // Q
        int p0 = cvtpk(acc[0][0], acc[0][1]);
        int p1 = cvtpk(acc[0][2], acc[0][3]);
        int p2 = cvtpk(acc[0][4], acc[0][5]);
        int p3 = cvtpk(acc[0][6], acc[0][7]);
        int p4 = cvtpk(acc[0][8], acc[0][9]);
        i32x4* dst = (i32x4*)qo + srow * 2;
        dst[0] = (i32x4){p0, p1, p2, p3};
        dst[1] = (i32x4){p4, 0, 0, 0};
    }
    {   // K
        int p0 = cvtpk(acc[1][0], acc[1][1]);
        int p1 = cvtpk(acc[1][2], acc[1][3]);
        int p2 = cvtpk(acc[1][4], acc[1][5]);
        int p3 = cvtpk(acc[1][6], acc[1][7]);
        int p4 = cvtpk(acc[1][8], acc[1][9]);
        i32x4* dst = (i32x4*)ko + srow * 2;
        dst[0] = (i32x4){p0, p1, p2, p3};
        dst[1] = (i32x4){p4, 0, 0, 0};
    }
    {   // V^T scatter by d-row
        int p0 = cvtpk(acc[2][0], acc[2][1]);
        int p1 = cvtpk(acc[2][2], acc[2][3]);
        int p2 = cvtpk(acc[2][4], acc[2][5]);
        int p3 = cvtpk(acc[2][6], acc[2][7]);
        int p4 = cvtpk(acc[2][8], acc[2][9]);
        unsigned short* vb = vt + ((size_t)(b4 + hp) * 16) * 512 + (s0 + lane);
        vb[0 * 512] = (unsigned short)(p0 & 0xffff);
        vb[1 * 512] = (unsigned short)((unsigned)p0 >> 16);
        vb[2 * 512] = (unsigned short)(p1 & 0xffff);
        vb[3 * 512] = (unsigned short)((unsigned)p1 >> 16);
        vb[4 * 512] = (unsigned short)(p2 & 0xffff);
        vb[5 * 512] = (unsigned short)((unsigned)p2 >> 16);
        vb[6 * 512] = (unsigned short)(p3 & 0xffff);
        vb[7 * 512] = (unsigned short)((unsigned)p3 >> 16);
        vb[8 * 512] = (unsigned short)(p4 & 0xffff);
        vb[9 * 512] = (unsigned short)((unsigned)p4 >> 16);
        vb[10 * 512] = 0x3F80;   // bf16(1.0) ones-row -> denominator
        vb[11 * 512] = 0; vb[12 * 512] = 0; vb[13 * 512] = 0;
        vb[14 * 512] = 0; vb[15 * 512] = 0;
    }
}

// ---------------- K2: attention v13 (MFMA, 1 block/bh) ----------------
// grid 256 = bh. block 512 = 8 waves; wave owns 64 q (2 tiles of 32).
// Changes vs v12 (which ran ~25us inferred): (1) K/V staged once per bh,
// not twice; (2) K fragments read DIRECTLY from global, software-
// pipelined (prefetch kt+1) -- drops K LDS staging and its 4-way-conflict
// ds_read pattern (48B stride => bank 12r mod 32, period 8); K is 16KB,
// L2-resident, coalesced 1KB/wave/iter; (3) epilogue v_rcp+mul replaces
// 32 full divides/lane. V^T stays in LDS (1040B stride = 2-way = free).
__global__ __launch_bounds__(512) void k_attn(
    const unsigned short* __restrict__ qg, const unsigned short* __restrict__ kg,
    const unsigned short* __restrict__ vt, float* __restrict__ ctx)
{
    __shared__ __align__(16) char smem[16640];   // V^T: 16 rows x 1040B

    const int tid = threadIdx.x;
    const int bh = blockIdx.x;
    const int lane = tid & 63;
    const int wavei = tid >> 6;

    // Q fragments (B-operand: lane l -> Q[q=l&31][d=(l>>5)*8+j])
    bh8 qf0, qf1;
    {
        const char* qp = (const char*)qg + (size_t)bh * 512 * 32;
        const int qbase = wavei * 64;
        qf0 = *(const bh8*)(qp + (size_t)(qbase + (lane & 31)) * 32 + (lane >> 5) * 16);
        qf1 = *(const bh8*)(qp + (size_t)(qbase + 32 + (lane & 31)) * 32 + (lane >> 5) * 16);
    }
    // stage V^T (1024 x 16B chunks -> 1040B rows)
    {
        const i32x4* gv = (const i32x4*)((const char*)vt + (size_t)bh * 16 * 1024);
        for (int c = tid; c < 1024; c += 512) {
            i32x4 u = gv[c];
            *(i32x4*)(smem + (c >> 6) * 1040 + (c & 63) * 16) = u;
        }
    }
    __syncthreads();

    const char* sV = smem;
    const int krow = lane & 31, khalf = lane >> 5;
    const int vrow = lane & 15;
    const bool vzero = (lane & 16) != 0;   // B cols d>=16 must be zero

    const bh8* gk = (const bh8*)((const char*)kg + (size_t)bh * 512 * 32);

    fx16 acc0 = (fx16)(0.0f), acc1 = (fx16)(0.0f);

    bh8 kf = gk[(size_t)krow * 2 + khalf];          // kt = 0 prefetch
    for (int kt = 0; kt < 16; ++kt) {               // 32 keys / iter
        bh8 kfn = kf;
        if (kt < 15) kfn = gk[(size_t)((kt + 1) * 32 + krow) * 2 + khalf];
        bh8 vf0 = *(const bh8*)(sV + vrow * 1040 + kt * 64 + khalf * 16);
        bh8 vf1 = *(const bh8*)(sV + vrow * 1040 + kt * 64 + 32 + khalf * 16);
        if (vzero) { vf0 = (bh8)(short)0; vf1 = (bh8)(short)0; }
#pragma unroll
        for (int qt = 0; qt < 2; ++qt) {
            fx16 s = __builtin_amdgcn_mfma_f32_32x32x16_bf16(
                kf, qt ? qf1 : qf0, (fx16)(0.0f), 0, 0, 0);
            float e[16];
#pragma unroll
            for (int r = 0; r < 16; ++r) e[r] = __builtin_amdgcn_exp2f(s[r]);
            int c0 = cvtpk(e[0], e[1]),   c1 = cvtpk(e[2], e[3]);
            int c2 = cvtpk(e[4], e[5]),   c3 = cvtpk(e[6], e[7]);
            int c4 = cvtpk(e[8], e[9]),   c5 = cvtpk(e[10], e[11]);
            int c6 = cvtpk(e[12], e[13]), c7 = cvtpk(e[14], e[15]);
            // redistribute P across the 32-lane halves into A-operand order
            asm("v_permlane32_swap_b32 %0, %1" : "+v"(c0), "+v"(c2));
            asm("v_permlane32_swap_b32 %0, %1" : "+v"(c1), "+v"(c3));
            asm("v_permlane32_swap_b32 %0, %1" : "+v"(c4), "+v"(c6));
            asm("v_permlane32_swap_b32 %0, %1" : "+v"(c5), "+v"(c7));
            union { i32x4 i; bh8 h; } lo, hi;
            lo.i = (i32x4){c0, c1, c2, c3};   // P[q][k 0..15 of this kt]
            hi.i = (i32x4){c4, c5, c6, c7};   // P[q][k 16..31]
            if (qt == 0) {
                acc0 = __builtin_amdgcn_mfma_f32_32x32x16_bf16(lo.h, vf0, acc0, 0, 0, 0);
                acc0 = __builtin_amdgcn_mfma_f32_32x32x16_bf16(hi.h, vf1, acc0, 0, 0, 0);
            } else {
                acc1 = __builtin_amdgcn_mfma_f32_32x32x16_bf16(lo.h, vf0, acc1, 0, 0, 0);
                acc1 = __builtin_amdgcn_mfma_f32_32x32x16_bf16(hi.h, vf1, acc1, 0, 0, 0);
            }
        }
        kf = kfn;
    }

    // epilogue: col 10 holds denominator; broadcast in 32-group, rcp, store
    const int d = lane & 31;
    const int qb = wavei * 64;
#pragma unroll
    for (int qt = 0; qt < 2; ++qt) {
        fx16 A = qt ? acc1 : acc0;
#pragma unroll
        for (int r = 0; r < 16; ++r) {
            float v = A[r];
            float ls = __shfl(v, (lane & 32) | 10, 64);
            float o = v * fastrcp(ls);
            if (d < 10) {
                int q = qb + qt * 32 + (r & 3) + 8 * (r >> 2) + 4 * (lane >> 5);
                ctx[((size_t)bh * 512 + q) * 10 + d] = o;
            }
        }
    }
}

// ---------------- K3: Wo + residual + LN2 + FFN + residual ----------------
// grid 512 x 256. Block = 64 rows; wave = col-slice, lane = row. (unchanged)
__global__ __launch_bounds__(256) void k_out_ffn(
    const float* __restrict__ ctx, const float* __restrict__ x,
    const float* __restrict__ Wo, const float* __restrict__ bo,
    const float* __restrict__ g2, const float* __restrict__ bt2,
    const float* __restrict__ W1, const float* __restrict__ b1,
    const float* __restrict__ W2, const float* __restrict__ b2,
    float* __restrict__ out)
{
    __shared__ float sWo[40][48];
    __shared__ float sW1[40][32];
    __shared__ float sW2[20][48];
    __shared__ float sBo[40], sG2[40], sBt2[40], sB1[20], sB2[40];
    __shared__ float sCtx[64][41];
    __shared__ float sH[64][41];
    __shared__ float sIt[64][21];
    __shared__ float sSum[64][4], sSum2[64][4];

    const int tid = threadIdx.x;
    for (int idx = tid; idx < 1600; idx += 256) {
        int i = idx / 40, j = idx % 40;
        sWo[i][(j / 10) * 12 + (j % 10)] = Wo[idx];
    }
    for (int idx = tid; idx < 800; idx += 256) {
        {
            int i = idx / 20, j = idx % 20;
            sW1[i][(j / 5) * 8 + (j % 5)] = W1[idx];
        }
        {
            int i = idx / 40, j = idx % 40;
            sW2[i][(j / 10) * 12 + (j % 10)] = W2[idx];
        }
    }
    if (tid < 40) { sBo[tid] = bo[tid]; sG2[tid] = g2[tid]; sBt2[tid] = bt2[tid]; sB2[tid] = b2[tid]; }
    if (tid < 20) sB1[tid] = b1[tid];

    const int row0 = blockIdx.x * 64;
    const int b = row0 >> 9, s0 = row0 & 511;

    for (int idx = tid; idx < 640; idx += 256) {
        const int hh = idx / 160, f = idx - hh * 160;
        float4 u = *(const float4*)(ctx + ((size_t)((b * 4 + hh) * 512 + s0)) * 10 + f * 4);
        const int fo = f * 4;
        float e[4] = {u.x, u.y, u.z, u.w};
#pragma unroll
        for (int t = 0; t < 4; t++) {
            const int fe = fo + t;
            const int r = fe / 10, c = fe - r * 10;
            sCtx[r][hh * 10 + c] = e[t];
        }
    }
    const float4* xblk = (const float4*)(x + (size_t)blockIdx.x * 64 * 40);
    for (int idx = tid; idx < 640; idx += 256) {
        float4 w = xblk[idx];
        int fl = idx * 4;
        int r = fl / 40, c = fl - r * 40;
        sH[r][c] = w.x; sH[r][c + 1] = w.y; sH[r][c + 2] = w.z; sH[r][c + 3] = w.w;
    }
    __syncthreads();

    const int lane = tid & 63;
    const int wv = tid >> 6;
    const int j0 = wv * 10;

    float acc[10];
#pragma unroll
    for (int j = 0; j < 10; j++) acc[j] = sBo[j0 + j] + sH[lane][j0 + j];
#pragma unroll 8
    for (int i = 0; i < 40; i++) {
        const float ci = sCtx[lane][i];
        const float4* wrow = (const float4*)&sWo[i][wv * 12];
        float4 w0 = wrow[0], w1 = wrow[1], w2 = wrow[2];
        acc[0] += ci * w0.x; acc[1] += ci * w0.y; acc[2] += ci * w0.z; acc[3] += ci * w0.w;
        acc[4] += ci * w1.x; acc[5] += ci * w1.y; acc[6] += ci * w1.z; acc[7] += ci * w1.w;
        acc[8] += ci * w2.x; acc[9] += ci * w2.y;
    }
    {
        float s1 = 0.f, s2 = 0.f;
#pragma unroll
        for (int j = 0; j < 10; j++) { s1 += acc[j]; s2 += acc[j] * acc[j]; }
        sSum[lane][wv] = s1; sSum2[lane][wv] = s2;
    }
    __syncthreads();
    const float mu = (sSum[lane][0] + sSum[lane][1] + sSum[lane][2] + sSum[lane][3]) * 0.025f;
    const float ex2 = (sSum2[lane][0] + sSum2[lane][1] + sSum2[lane][2] + sSum2[lane][3]) * 0.025f;
    const float rs = rsqrtf(ex2 - mu * mu + EPSF);
#pragma unroll
    for (int j = 0; j < 10; j++)
        sH[lane][j0 + j] = (acc[j] - mu) * rs * sG2[j0 + j] + sBt2[j0 + j];
    __syncthreads();

    const int f0 = wv * 5;
    float it[5];
#pragma unroll
    for (int j = 0; j < 5; j++) it[j] = sB1[f0 + j];
#pragma unroll 8
    for (int i = 0; i < 40; i++) {
        const float hi = sH[lane][i];
        const float4* wrow = (const float4*)&sW1[i][wv * 8];
        float4 w0 = wrow[0], w1 = wrow[1];
        it[0] += hi * w0.x; it[1] += hi * w0.y; it[2] += hi * w0.z; it[3] += hi * w0.w;
        it[4] += hi * w1.x;
    }
#pragma unroll
    for (int j = 0; j < 5; j++) {
        float t = it[j];
        sIt[lane][f0 + j] = 0.5f * t * (1.0f + erff(t * 0.70710678118654752f));
    }
    __syncthreads();

    float o[10];
#pragma unroll
    for (int j = 0; j < 10; j++) o[j] = acc[j] + sB2[j0 + j];
#pragma unroll 4
    for (int i = 0; i < 20; i++) {
        const float ii = sIt[lane][i];
        const float4* wrow = (const float4*)&sW2[i][wv * 12];
        float4 w0 = wrow[0], w1 = wrow[1], w2 = wrow[2];
        o[0] += ii * w0.x; o[1] += ii * w0.y; o[2] += ii * w0.z; o[3] += ii * w0.w;
        o[4] += ii * w1.x; o[5] += ii * w1.y; o[6] += ii * w1.z; o[7] += ii * w1.w;
        o[8] += ii * w2.x; o[9] += ii * w2.y;
    }
#pragma unroll
    for (int j = 0; j < 10; j++) sCtx[lane][j0 + j] = o[j];
    __syncthreads();

    float4* oblk = (float4*)(out + (size_t)blockIdx.x * 64 * 40);
    for (int idx = tid; idx < 640; idx += 256) {
        int fl = idx * 4;
        int r = fl / 40, c = fl - r * 40;
        float4 u;
        u.x = sCtx[r][c]; u.y = sCtx[r][c + 1]; u.z = sCtx[r][c + 2]; u.w = sCtx[r][c + 3];
        oblk[idx] = u;
    }
}

extern "C" void kernel_launch(void* const* d_in, const int* in_sizes, int n_in,
                              void* d_out, int out_size, void* d_ws, size_t ws_size,
                              hipStream_t stream)
{
    const float* x   = (const float*)d_in[0];
    const float* g1  = (const float*)d_in[1];
    const float* be1 = (const float*)d_in[2];
    const float* Wq  = (const float*)d_in[3];
    const float* bq  = (const float*)d_in[4];
    const float* Wk  = (const float*)d_in[5];
    const float* bk  = (const float*)d_in[6];
    const float* Wv  = (const float*)d_in[7];
    const float* bv  = (const float*)d_in[8];
    const float* Wo  = (const float*)d_in[9];
    const float* bo  = (const float*)d_in[10];
    const float* g2  = (const float*)d_in[11];
    const float* bt2 = (const float*)d_in[12];
    const float* W1  = (const float*)d_in[13];
    const float* b1  = (const float*)d_in[14];
    const float* W2  = (const float*)d_in[15];
    const float* b2  = (const float*)d_in[16];

    unsigned short* wsu = (unsigned short*)d_ws;
    const size_t T = (size_t)256 * 512 * 16;   // 4 MB per bf16 tensor
    unsigned short* q  = wsu;
    unsigned short* k  = wsu + T;
    unsigned short* vt = wsu + 2 * T;
    float* ctx = (float*)(wsu + 3 * T);        // [B*H][S][10] f32

    k_ln_qkv<<<512, 256, 0, stream>>>(x, g1, be1, Wq, bq, Wk, bk, Wv, bv, q, k, vt);
    k_attn<<<256, 512, 0, stream>>>(q, k, vt, ctx);
    k_out_ffn<<<512, 256, 0, stream>>>(ctx, x, Wo, bo, g2, bt2, W1, b1, W2, b2,
                                       (float*)d_out);
}

// Round 10
// 129.727 us; speedup vs baseline: 2.8443x; 1.0690x over previous
//
#include <hip/hip_runtime.h>
#include <stdint.h>

#define EPSF 1e-5f

typedef __attribute__((ext_vector_type(8)))  short bh8;    // 8 bf16 = 4 VGPR
typedef __attribute__((ext_vector_type(16))) float fx16;   // 32x32 MFMA acc
typedef __attribute__((ext_vector_type(4)))  int   i32x4;

__device__ __forceinline__ int cvtpk(float a, float b) {
    int r;
    asm("v_cvt_pk_bf16_f32 %0, %1, %2" : "=v"(r) : "v"(a), "v"(b));
    return r;
}
__device__ __forceinline__ float fastrcp(float x) {
    float r;
    asm("v_rcp_f32 %0, %1" : "=v"(r) : "v"(x));
    return r;
}

// ---------------- K12: LN1 + QKV (head-sliced) + MFMA attention ----------------
// grid 256 = (b,h). block 512. The k1->k2 dependency is made block-local by
// slicing k1 per head: this block computes LN+QKV for all 512 rows of batch b,
// head h ONLY (weight slice is block-uniform -> s_load), writes K/V^T/Q into
// LDS, then runs the v13 attention verbatim. Q/K/V never touch HBM.
// LDS: phase A sX[512][41] f32 = 84KB; phase B reuses it:
//   sK 512x48B = 24576 | sVT 16x1040B = 16640 | sQ 512x32B = 16384.
__global__ __launch_bounds__(512) void k_qkv_attn(
    const float* __restrict__ x, const float* __restrict__ g, const float* __restrict__ be,
    const float* __restrict__ Wq, const float* __restrict__ bq,
    const float* __restrict__ Wk, const float* __restrict__ bk,
    const float* __restrict__ Wv, const float* __restrict__ bv,
    float* __restrict__ ctx)
{
    __shared__ __align__(16) char smem[83968];

    const int tid = threadIdx.x;
    const int bh = blockIdx.x;
    const int b  = bh >> 2;
    const int h  = bh & 3;               // block-uniform head index
    const int lane = tid & 63;
    const int wavei = tid >> 6;

    // ---- Phase A: stage x[b] (512 x 40 f32) ----
    float* sX = (float*)smem;
    {
        const float4* xb = (const float4*)(x + (size_t)b * 512 * 40);
        for (int idx = tid; idx < 5120; idx += 512) {
            float4 u = xb[idx];
            int fl = idx * 4;
            int r = fl / 40, c = fl - r * 40;
            sX[r * 41 + c] = u.x; sX[r * 41 + c + 1] = u.y;
            sX[r * 41 + c + 2] = u.z; sX[r * 41 + c + 3] = u.w;
        }
    }
    __syncthreads();

    // LN + QKV for row `tid`, head h only
    float s1 = 0.f, s2 = 0.f;
#pragma unroll 8
    for (int i = 0; i < 40; i++) { float v = sX[tid * 41 + i]; s1 += v; s2 += v * v; }
    const float mu = s1 * 0.025f;
    const float rs = rsqrtf(s2 * 0.025f - mu * mu + EPSF);

    float hrow[40];
#pragma unroll 4
    for (int i = 0; i < 40; i++)
        hrow[i] = (sX[tid * 41 + i] - mu) * rs * g[i] + be[i];

    float aq[10], ak[10], av[10];
#pragma unroll
    for (int c = 0; c < 10; c++) {
        aq[c] = bq[h * 10 + c]; ak[c] = bk[h * 10 + c]; av[c] = bv[h * 10 + c];
    }
#pragma unroll 2
    for (int i = 0; i < 40; i++) {
        const float hi = hrow[i];
        const float* wq = Wq + i * 40 + h * 10;   // uniform -> s_load
        const float* wk = Wk + i * 40 + h * 10;
        const float* wv = Wv + i * 40 + h * 10;
#pragma unroll
        for (int c = 0; c < 10; c++) {
            aq[c] += hi * wq[c]; ak[c] += hi * wk[c]; av[c] += hi * wv[c];
        }
    }
    const float cs = 1.4426950408889634f / 3.1622776601683795f;  // log2e/sqrt(10)
#pragma unroll
    for (int c = 0; c < 10; c++) aq[c] *= cs;

    __syncthreads();   // all sX reads done -> safe to overlay

    // ---- write K / V^T / Q into LDS ----
    char* sK  = smem;                    // [512] rows x 48B (32B data + pad)
    char* sVT = smem + 24576;            // [16] rows x 1040B (ones-row at d=10)
    char* sQ  = smem + 41216;            // [512] rows x 32B
    {
        int p0 = cvtpk(ak[0], ak[1]), p1 = cvtpk(ak[2], ak[3]);
        int p2 = cvtpk(ak[4], ak[5]), p3 = cvtpk(ak[6], ak[7]);
        int p4 = cvtpk(ak[8], ak[9]);
        i32x4* kd = (i32x4*)(sK + tid * 48);
        kd[0] = (i32x4){p0, p1, p2, p3};
        kd[1] = (i32x4){p4, 0, 0, 0};
    }
    {
        int p0 = cvtpk(aq[0], aq[1]), p1 = cvtpk(aq[2], aq[3]);
        int p2 = cvtpk(aq[4], aq[5]), p3 = cvtpk(aq[6], aq[7]);
        int p4 = cvtpk(aq[8], aq[9]);
        i32x4* qd = (i32x4*)(sQ + tid * 32);
        qd[0] = (i32x4){p0, p1, p2, p3};
        qd[1] = (i32x4){p4, 0, 0, 0};
    }
    {
        int p0 = cvtpk(av[0], av[1]), p1 = cvtpk(av[2], av[3]);
        int p2 = cvtpk(av[4], av[5]), p3 = cvtpk(av[6], av[7]);
        int p4 = cvtpk(av[8], av[9]);
        unsigned short* vb = (unsigned short*)sVT + tid;   // column tid, 520-short rows
        vb[0 * 520] = (unsigned short)(p0 & 0xffff);
        vb[1 * 520] = (unsigned short)((unsigned)p0 >> 16);
        vb[2 * 520] = (unsigned short)(p1 & 0xffff);
        vb[3 * 520] = (unsigned short)((unsigned)p1 >> 16);
        vb[4 * 520] = (unsigned short)(p2 & 0xffff);
        vb[5 * 520] = (unsigned short)((unsigned)p2 >> 16);
        vb[6 * 520] = (unsigned short)(p3 & 0xffff);
        vb[7 * 520] = (unsigned short)((unsigned)p3 >> 16);
        vb[8 * 520] = (unsigned short)(p4 & 0xffff);
        vb[9 * 520] = (unsigned short)((unsigned)p4 >> 16);
        vb[10 * 520] = 0x3F80;   // bf16(1.0) ones-row -> denominator
        vb[11 * 520] = 0; vb[12 * 520] = 0; vb[13 * 520] = 0;
        vb[14 * 520] = 0; vb[15 * 520] = 0;
    }
    __syncthreads();

    // ---- Phase B: attention (v13 math, all operands in LDS) ----
    const int krow = lane & 31, khalf = lane >> 5;
    const int vrow = lane & 15;
    const bool vzero = (lane & 16) != 0;

    bh8 qf0 = *(const bh8*)(sQ + (size_t)(wavei * 64 + (lane & 31)) * 32 + (lane >> 5) * 16);
    bh8 qf1 = *(const bh8*)(sQ + (size_t)(wavei * 64 + 32 + (lane & 31)) * 32 + (lane >> 5) * 16);

    fx16 acc0 = (fx16)(0.0f), acc1 = (fx16)(0.0f);

    for (int kt = 0; kt < 16; ++kt) {      // 32 keys / iter
        bh8 kf  = *(const bh8*)(sK + (kt * 32 + krow) * 48 + khalf * 16);
        bh8 vf0 = *(const bh8*)(sVT + vrow * 1040 + kt * 64 + khalf * 16);
        bh8 vf1 = *(const bh8*)(sVT + vrow * 1040 + kt * 64 + 32 + khalf * 16);
        if (vzero) { vf0 = (bh8)(short)0; vf1 = (bh8)(short)0; }
#pragma unroll
        for (int qt = 0; qt < 2; ++qt) {
            fx16 s = __builtin_amdgcn_mfma_f32_32x32x16_bf16(
                kf, qt ? qf1 : qf0, (fx16)(0.0f), 0, 0, 0);
            float e[16];
#pragma unroll
            for (int r = 0; r < 16; ++r) e[r] = __builtin_amdgcn_exp2f(s[r]);
            int c0 = cvtpk(e[0], e[1]),   c1 = cvtpk(e[2], e[3]);
            int c2 = cvtpk(e[4], e[5]),   c3 = cvtpk(e[6], e[7]);
            int c4 = cvtpk(e[8], e[9]),   c5 = cvtpk(e[10], e[11]);
            int c6 = cvtpk(e[12], e[13]), c7 = cvtpk(e[14], e[15]);
            asm("v_permlane32_swap_b32 %0, %1" : "+v"(c0), "+v"(c2));
            asm("v_permlane32_swap_b32 %0, %1" : "+v"(c1), "+v"(c3));
            asm("v_permlane32_swap_b32 %0, %1" : "+v"(c4), "+v"(c6));
            asm("v_permlane32_swap_b32 %0, %1" : "+v"(c5), "+v"(c7));
            union { i32x4 i; bh8 h; } lo, hi;
            lo.i = (i32x4){c0, c1, c2, c3};   // P[q][k 0..15 of this kt]
            hi.i = (i32x4){c4, c5, c6, c7};   // P[q][k 16..31]
            if (qt == 0) {
                acc0 = __builtin_amdgcn_mfma_f32_32x32x16_bf16(lo.h, vf0, acc0, 0, 0, 0);
                acc0 = __builtin_amdgcn_mfma_f32_32x32x16_bf16(hi.h, vf1, acc0, 0, 0, 0);
            } else {
                acc1 = __builtin_amdgcn_mfma_f32_32x32x16_bf16(lo.h, vf0, acc1, 0, 0, 0);
                acc1 = __builtin_amdgcn_mfma_f32_32x32x16_bf16(hi.h, vf1, acc1, 0, 0, 0);
            }
        }
    }

    // epilogue: col 10 holds denominator; broadcast in 32-group, rcp, store
    const int d = lane & 31;
    const int qb = wavei * 64;
#pragma unroll
    for (int qt = 0; qt < 2; ++qt) {
        fx16 A = qt ? acc1 : acc0;
#pragma unroll
        for (int r = 0; r < 16; ++r) {
            float v = A[r];
            float ls = __shfl(v, (lane & 32) | 10, 64);
            float o = v * fastrcp(ls);
            if (d < 10) {
                int q = qb + qt * 32 + (r & 3) + 8 * (r >> 2) + 4 * (lane >> 5);
                ctx[((size_t)bh * 512 + q) * 10 + d] = o;
            }
        }
    }
}

// ---------------- K3: Wo + residual + LN2 + FFN + residual ----------------
// grid 512 x 256. Block = 64 rows; wave = col-slice, lane = row. (unchanged)
__global__ __launch_bounds__(256) void k_out_ffn(
    const float* __restrict__ ctx, const float* __restrict__ x,
    const float* __restrict__ Wo, const float* __restrict__ bo,
    const float* __restrict__ g2, const float* __restrict__ bt2,
    const float* __restrict__ W1, const float* __restrict__ b1,
    const float* __restrict__ W2, const float* __restrict__ b2,
    float* __restrict__ out)
{
    __shared__ float sWo[40][48];
    __shared__ float sW1[40][32];
    __shared__ float sW2[20][48];
    __shared__ float sBo[40], sG2[40], sBt2[40], sB1[20], sB2[40];
    __shared__ float sCtx[64][41];
    __shared__ float sH[64][41];
    __shared__ float sIt[64][21];
    __shared__ float sSum[64][4], sSum2[64][4];

    const int tid = threadIdx.x;
    for (int idx = tid; idx < 1600; idx += 256) {
        int i = idx / 40, j = idx % 40;
        sWo[i][(j / 10) * 12 + (j % 10)] = Wo[idx];
    }
    for (int idx = tid; idx < 800; idx += 256) {
        {
            int i = idx / 20, j = idx % 20;
            sW1[i][(j / 5) * 8 + (j % 5)] = W1[idx];
        }
        {
            int i = idx / 40, j = idx % 40;
            sW2[i][(j / 10) * 12 + (j % 10)] = W2[idx];
        }
    }
    if (tid < 40) { sBo[tid] = bo[tid]; sG2[tid] = g2[tid]; sBt2[tid] = bt2[tid]; sB2[tid] = b2[tid]; }
    if (tid < 20) sB1[tid] = b1[tid];

    const int row0 = blockIdx.x * 64;
    const int b = row0 >> 9, s0 = row0 & 511;

    for (int idx = tid; idx < 640; idx += 256) {
        const int hh = idx / 160, f = idx - hh * 160;
        float4 u = *(const float4*)(ctx + ((size_t)((b * 4 + hh) * 512 + s0)) * 10 + f * 4);
        const int fo = f * 4;
        float e[4] = {u.x, u.y, u.z, u.w};
#pragma unroll
        for (int t = 0; t < 4; t++) {
            const int fe = fo + t;
            const int r = fe / 10, c = fe - r * 10;
            sCtx[r][hh * 10 + c] = e[t];
        }
    }
    const float4* xblk = (const float4*)(x + (size_t)blockIdx.x * 64 * 40);
    for (int idx = tid; idx < 640; idx += 256) {
        float4 w = xblk[idx];
        int fl = idx * 4;
        int r = fl / 40, c = fl - r * 40;
        sH[r][c] = w.x; sH[r][c + 1] = w.y; sH[r][c + 2] = w.z; sH[r][c + 3] = w.w;
    }
    __syncthreads();

    const int lane = tid & 63;
    const int wv = tid >> 6;
    const int j0 = wv * 10;

    float acc[10];
#pragma unroll
    for (int j = 0; j < 10; j++) acc[j] = sBo[j0 + j] + sH[lane][j0 + j];
#pragma unroll 8
    for (int i = 0; i < 40; i++) {
        const float ci = sCtx[lane][i];
        const float4* wrow = (const float4*)&sWo[i][wv * 12];
        float4 w0 = wrow[0], w1 = wrow[1], w2 = wrow[2];
        acc[0] += ci * w0.x; acc[1] += ci * w0.y; acc[2] += ci * w0.z; acc[3] += ci * w0.w;
        acc[4] += ci * w1.x; acc[5] += ci * w1.y; acc[6] += ci * w1.z; acc[7] += ci * w1.w;
        acc[8] += ci * w2.x; acc[9] += ci * w2.y;
    }
    {
        float s1 = 0.f, s2 = 0.f;
#pragma unroll
        for (int j = 0; j < 10; j++) { s1 += acc[j]; s2 += acc[j] * acc[j]; }
        sSum[lane][wv] = s1; sSum2[lane][wv] = s2;
    }
    __syncthreads();
    const float mu = (sSum[lane][0] + sSum[lane][1] + sSum[lane][2] + sSum[lane][3]) * 0.025f;
    const float ex2 = (sSum2[lane][0] + sSum2[lane][1] + sSum2[lane][2] + sSum2[lane][3]) * 0.025f;
    const float rs = rsqrtf(ex2 - mu * mu + EPSF);
#pragma unroll
    for (int j = 0; j < 10; j++)
        sH[lane][j0 + j] = (acc[j] - mu) * rs * sG2[j0 + j] + sBt2[j0 + j];
    __syncthreads();

    const int f0 = wv * 5;
    float it[5];
#pragma unroll
    for (int j = 0; j < 5; j++) it[j] = sB1[f0 + j];
#pragma unroll 8
    for (int i = 0; i < 40; i++) {
        const float hi = sH[lane][i];
        const float4* wrow = (const float4*)&sW1[i][wv * 8];
        float4 w0 = wrow[0], w1 = wrow[1];
        it[0] += hi * w0.x; it[1] += hi * w0.y; it[2] += hi * w0.z; it[3] += hi * w0.w;
        it[4] += hi * w1.x;
    }
#pragma unroll
    for (int j = 0; j < 5; j++) {
        float t = it[j];
        sIt[lane][f0 + j] = 0.5f * t * (1.0f + erff(t * 0.70710678118654752f));
    }
    __syncthreads();

    float o[10];
#pragma unroll
    for (int j = 0; j < 10; j++) o[j] = acc[j] + sB2[j0 + j];
#pragma unroll 4
    for (int i = 0; i < 20; i++) {
        const float ii = sIt[lane][i];
        const float4* wrow = (const float4*)&sW2[i][wv * 12];
        float4 w0 = wrow[0], w1 = wrow[1], w2 = wrow[2];
        o[0] += ii * w0.x; o[1] += ii * w0.y; o[2] += ii * w0.z; o[3] += ii * w0.w;
        o[4] += ii * w1.x; o[5] += ii * w1.y; o[6] += ii * w1.z; o[7] += ii * w1.w;
        o[8] += ii * w2.x; o[9] += ii * w2.y;
    }
#pragma unroll
    for (int j = 0; j < 10; j++) sCtx[lane][j0 + j] = o[j];
    __syncthreads();

    float4* oblk = (float4*)(out + (size_t)blockIdx.x * 64 * 40);
    for (int idx = tid; idx < 640; idx += 256) {
        int fl = idx * 4;
        int r = fl / 40, c = fl - r * 40;
        float4 u;
        u.x = sCtx[r][c]; u.y = sCtx[r][c + 1]; u.z = sCtx[r][c + 2]; u.w = sCtx[r][c + 3];
        oblk[idx] = u;
    }
}

extern "C" void kernel_launch(void* const* d_in, const int* in_sizes, int n_in,
                              void* d_out, int out_size, void* d_ws, size_t ws_size,
                              hipStream_t stream)
{
    const float* x   = (const float*)d_in[0];
    const float* g1  = (const float*)d_in[1];
    const float* be1 = (const float*)d_in[2];
    const float* Wq  = (const float*)d_in[3];
    const float* bq  = (const float*)d_in[4];
    const float* Wk  = (const float*)d_in[5];
    const float* bk  = (const float*)d_in[6];
    const float* Wv  = (const float*)d_in[7];
    const float* bv  = (const float*)d_in[8];
    const float* Wo  = (const float*)d_in[9];
    const float* bo  = (const float*)d_in[10];
    const float* g2  = (const float*)d_in[11];
    const float* bt2 = (const float*)d_in[12];
    const float* W1  = (const float*)d_in[13];
    const float* b1  = (const float*)d_in[14];
    const float* W2  = (const float*)d_in[15];
    const float* b2  = (const float*)d_in[16];

    float* ctx = (float*)d_ws;   // [B*H][S][10] f32 = 5.24 MB

    k_qkv_attn<<<256, 512, 0, stream>>>(x, g1, be1, Wq, bq, Wk, bk, Wv, bv, ctx);
    k_out_ffn<<<512, 256, 0, stream>>>(ctx, x, Wo, bo, g2, bt2, W1, b1, W2, b2,
                                       (float*)d_out);
}